// Round 9
// baseline (469.105 us; speedup 1.0000x reference)
//
#include <hip/hip_runtime.h>
#include <hip/hip_bf16.h>
#include <math.h>

#define N_NODES 100000
#define N_EDGES 3200000
#define IN_FEATS 256
#define N_UNITS 32
#define OUT_FEATS 40

#define NPB 64                       // nodes per fine bucket
#define BSHIFT 6                     // dst >> 6 = fine bucket
#define NB 1563                      // ceil(100000/64) fine buckets
#define CAP 4096                     // max edges per fine bucket (avg 2048)

#define NC 49                        // coarse buckets (2048 nodes each)
#define CSHIFT 11                    // dst >> 11 = coarse bucket
#define CHUNK 8192                   // edges per bin block
#define NBLK ((N_EDGES + CHUNK - 1) / CHUNK)   // 391
#define WIN 128                      // fine-bucket window in pass B

// gemm split: half the nodes ride with binA, half with binB (binB only needs
// binA's completed output; gemm halves are independent of both)
#define GHALF 391                    // gemm blocks per half (391*128 = 50048 nodes)
#define NSPLIT (GHALF * 128)         // 50048

#define EC_NBLK 512                  // edgecount blocks

// ================= K0: single-pass edge counting =================
// Replaces the 2-slice LDS outdeg histogram + partials round-trip (~50MB of
// bookkeeping traffic) with fire-and-forget global atomics (3.2M adds spread
// over 100K addresses, ~32 avg, no hotspots) + the dst fine-bucket LDS count
// in the same pass. inv_out is never materialized: consumers compute
// rsqrt(max(deg,1)) on the fly (bit-identical math, 1 VALU op).
__global__ void __launch_bounds__(256) edgecount_kernel(const int* __restrict__ src,
                                                        const int* __restrict__ dst,
                                                        int* __restrict__ outdeg,
                                                        int* __restrict__ bucket_count) {
    __shared__ int lh[NB];
    for (int i = threadIdx.x; i < NB; i += 256) lh[i] = 0;
    __syncthreads();
    const int4* s4 = (const int4*)src;
    const int4* d4 = (const int4*)dst;
    const int total4 = N_EDGES / 4;
    for (int i = blockIdx.x * 256 + threadIdx.x; i < total4; i += EC_NBLK * 256) {
        int4 s = s4[i];
        int4 v = d4[i];
        atomicAdd(&outdeg[s.x], 1);
        atomicAdd(&outdeg[s.y], 1);
        atomicAdd(&outdeg[s.z], 1);
        atomicAdd(&outdeg[s.w], 1);
        atomicAdd(&lh[v.x >> BSHIFT], 1);
        atomicAdd(&lh[v.y >> BSHIFT], 1);
        atomicAdd(&lh[v.z >> BSHIFT], 1);
        atomicAdd(&lh[v.w >> BSHIFT], 1);
    }
    __syncthreads();
    for (int i = threadIdx.x; i < NB; i += 256)
        if (lh[i]) atomicAdd(&bucket_count[i], lh[i]);
}

// ================= K1: exclusive scan of fine counts; derive coarse bases =================
__global__ void __launch_bounds__(1024) scan_kernel(const int* __restrict__ bucket_count,
                                                    int* __restrict__ gbase,
                                                    int* __restrict__ gcursor,
                                                    int* __restrict__ gbaseA,
                                                    int* __restrict__ gcursorA) {
    __shared__ int ps[1024];
    int t = threadIdx.x;
    int i0 = 2 * t, i1 = 2 * t + 1;
    int a = (i0 < NB) ? bucket_count[i0] : 0;
    int b = (i1 < NB) ? bucket_count[i1] : 0;
    ps[t] = a + b;
    __syncthreads();
    for (int off = 1; off < 1024; off <<= 1) {
        int v = (t >= off) ? ps[t - off] : 0;
        __syncthreads();
        ps[t] += v;
        __syncthreads();
    }
    int excl = ps[t] - (a + b);
    if (i0 < NB) { gbase[i0] = excl; gcursor[i0] = excl; }
    if (i1 <= NB) { gbase[i1] = excl + a; if (i1 < NB) gcursor[i1] = excl + a; }
    __syncthreads();
    if (t < NC) { int v = gbase[t * 32]; gbaseA[t] = v; gcursorA[t] = v; }
    if (t == NC) gbaseA[NC] = N_EDGES;
}

// ---- shared gemm body for the two fused binning+gemm kernels ----
__device__ __forceinline__ void gemm_body(char* smem, int tid, int gblk,
                                          const float* __restrict__ x,
                                          const float* __restrict__ W1,
                                          const int* __restrict__ outdeg,
                                          float* __restrict__ h, int nbase) {
    // v1 body (proven best standalone @60.6us): 4 thr/node x 8 cols, W in LDS.
    float* Ws = (float*)smem;               // 32 KB
    for (int idx = tid; idx < IN_FEATS * N_UNITS / 4; idx += 512)
        ((float4*)Ws)[idx] = ((const float4*)W1)[idx];
    __syncthreads();
    unsigned n = (unsigned)(nbase + gblk * 128) + (tid >> 2);
    if (n >= (unsigned)N_NODES) return;
    unsigned j0 = (tid & 3) * 8;
    float acc[8] = {0, 0, 0, 0, 0, 0, 0, 0};
    const float4* xr = (const float4*)(x + (size_t)n * IN_FEATS);
    #pragma unroll 4
    for (int k4 = 0; k4 < IN_FEATS / 4; ++k4) {
        float4 xv = xr[k4];
        const float* wk = Ws + (k4 * 4) * N_UNITS + j0;
        #pragma unroll
        for (int jj = 0; jj < 8; ++jj) acc[jj] = fmaf(xv.x, wk[jj], acc[jj]);
        #pragma unroll
        for (int jj = 0; jj < 8; ++jj) acc[jj] = fmaf(xv.y, wk[N_UNITS + jj], acc[jj]);
        #pragma unroll
        for (int jj = 0; jj < 8; ++jj) acc[jj] = fmaf(xv.z, wk[2 * N_UNITS + jj], acc[jj]);
        #pragma unroll
        for (int jj = 0; jj < 8; ++jj) acc[jj] = fmaf(xv.w, wk[3 * N_UNITS + jj], acc[jj]);
    }
    float io = rsqrtf(fmaxf((float)outdeg[n], 1.0f));
    float* hr = h + (size_t)n * N_UNITS + j0;
    #pragma unroll
    for (int jj = 0; jj < 8; ++jj) hr[jj] = acc[jj] * io;
}

// ================= K2: gemm(lower half) fused with coarse binning (binA) =================
__global__ void __launch_bounds__(512) binAgemm_kernel(const int* __restrict__ src,
                                                       const int* __restrict__ dst,
                                                       int* __restrict__ gcursorA,
                                                       unsigned* __restrict__ pairsA,
                                                       const float* __restrict__ x,
                                                       const float* __restrict__ W1,
                                                       const int* __restrict__ outdeg,
                                                       float* __restrict__ h) {
    __shared__ __align__(16) char smem[CHUNK * 4 + 4 * NC * 4];   // 32 KB + 784 B
    int tid = threadIdx.x;
    if (blockIdx.x < GHALF) {
        gemm_body(smem, tid, blockIdx.x, x, W1, outdeg, h, 0);
        return;
    }
    // ---- binA: coarse binning (49 bins), LDS sort + coalesced write ----
    unsigned* sortedA = (unsigned*)smem;
    int* hist   = (int*)(smem + CHUNK * 4);
    int* lstart = hist + NC;
    int* cur    = lstart + NC;
    int* gres   = cur + NC;
    int e0 = (blockIdx.x - GHALF) * CHUNK;
    int cnt = min(CHUNK, N_EDGES - e0);
    unsigned es[16], ed[16];
    #pragma unroll
    for (int r = 0; r < 16; ++r) {
        int idx = tid + 512 * r;
        if (idx < cnt) { es[r] = src[e0 + idx]; ed[r] = dst[e0 + idx]; }
    }
    if (tid < NC) hist[tid] = 0;
    __syncthreads();
    #pragma unroll
    for (int r = 0; r < 16; ++r) {
        int idx = tid + 512 * r;
        if (idx < cnt) atomicAdd(&hist[ed[r] >> CSHIFT], 1);
    }
    __syncthreads();
    if (tid < 64) {
        int v = (tid < NC) ? hist[tid] : 0;
        int inc = v;
        #pragma unroll
        for (int off = 1; off < 64; off <<= 1) {
            int u = __shfl_up(inc, off, 64);
            if ((tid & 63) >= off) inc += u;
        }
        if (tid < NC) {
            int ls = inc - v;
            lstart[tid] = ls;
            cur[tid] = ls;
            gres[tid] = atomicAdd(&gcursorA[tid], v) - ls;   // dest = gres[c] + i
        }
    }
    __syncthreads();
    #pragma unroll
    for (int r = 0; r < 16; ++r) {
        int idx = tid + 512 * r;
        if (idx < cnt) {
            int c = ed[r] >> CSHIFT;
            int pos = atomicAdd(&cur[c], 1);
            sortedA[pos] = es[r] | ((ed[r] & ((1u << CSHIFT) - 1)) << 17);
        }
    }
    __syncthreads();
    for (int i = tid; i < cnt; i += 512) {
        int lo = 0, hi = NC - 1;            // largest c with lstart[c] <= i
        while (lo < hi) { int mid = (lo + hi + 1) >> 1; if (lstart[mid] <= i) lo = mid; else hi = mid - 1; }
        pairsA[gres[lo] + i] = sortedA[i];
    }
}

// ================= K3: gemm(upper half) fused with fine binning (binB) =================
__global__ void __launch_bounds__(512) binBgemm_kernel(const unsigned* __restrict__ pairsA,
                                                       const int* __restrict__ gbaseA,
                                                       int* __restrict__ gcursor,
                                                       unsigned* __restrict__ pairs,
                                                       const float* __restrict__ x,
                                                       const float* __restrict__ W1,
                                                       const int* __restrict__ outdeg,
                                                       float* __restrict__ h) {
    __shared__ __align__(16) char smem[CHUNK * 4 + 4 * WIN * 4 + (NC + 2) * 4];  // ~35 KB
    int tid = threadIdx.x;
    if (blockIdx.x < GHALF) {
        gemm_body(smem, tid, blockIdx.x, x, W1, outdeg, h, NSPLIT);
        return;
    }
    unsigned* sortedB = (unsigned*)smem;
    int* hist   = (int*)(smem + CHUNK * 4);
    int* lstart = hist + WIN;
    int* cur    = lstart + WIN;
    int* gres   = cur + WIN;
    int* gA     = gres + WIN;                // NC+1 ints
    if (tid <= NC) gA[tid] = gbaseA[tid];
    if (tid < WIN) hist[tid] = 0;
    int e0 = (blockIdx.x - GHALF) * CHUNK;
    int cnt = min(CHUNK, N_EDGES - e0);
    __syncthreads();
    int c0 = 0;
    { int lo = 0, hi = NC - 1;
      while (lo < hi) { int mid = (lo + hi + 1) >> 1; if (gA[mid] <= e0) lo = mid; else hi = mid - 1; }
      c0 = lo; }
    int w0 = c0 * 32;
    unsigned pv[16]; short fw[16];
    int c = c0;
    #pragma unroll
    for (int r = 0; r < 16; ++r) {
        int idx = tid + 512 * r;
        if (idx < cnt) {
            int pos = e0 + idx;
            while (pos >= gA[c + 1]) ++c;
            unsigned p = pairsA[pos];
            unsigned srcid = p & 0x1FFFF;
            unsigned dl11 = (p >> 17) & 0x7FF;
            int wi = (c - c0) * 32 + (int)(dl11 >> 6);
            atomicAdd(&hist[wi], 1);
            pv[r] = srcid | ((dl11 & 63u) << 24);
            fw[r] = (short)wi;
        }
    }
    __syncthreads();
    if (tid < 64) {
        int v0 = hist[2 * tid], v1 = hist[2 * tid + 1];
        int s = v0 + v1;
        int inc = s;
        #pragma unroll
        for (int off = 1; off < 64; off <<= 1) {
            int u = __shfl_up(inc, off, 64);
            if ((tid & 63) >= off) inc += u;
        }
        int excl = inc - s;
        lstart[2 * tid] = excl;      cur[2 * tid] = excl;
        lstart[2 * tid + 1] = excl + v0; cur[2 * tid + 1] = excl + v0;
        int f0 = w0 + 2 * tid, f1 = f0 + 1;
        gres[2 * tid]     = (f0 < NB) ? (atomicAdd(&gcursor[f0], v0) - excl) : 0;
        gres[2 * tid + 1] = (f1 < NB) ? (atomicAdd(&gcursor[f1], v1) - (excl + v0)) : 0;
    }
    __syncthreads();
    #pragma unroll
    for (int r = 0; r < 16; ++r) {
        int idx = tid + 512 * r;
        if (idx < cnt) {
            int pos = atomicAdd(&cur[fw[r]], 1);
            sortedB[pos] = pv[r];
        }
    }
    __syncthreads();
    for (int i = tid; i < cnt; i += 512) {
        int lo = 0, hi = WIN - 1;
        while (lo < hi) { int mid = (lo + hi + 1) >> 1; if (lstart[mid] <= i) lo = mid; else hi = mid - 1; }
        pairs[gres[lo] + i] = sortedB[i];
    }
}

// ================= K5/K6: bucketed gather — LDS counting sort + register accumulation =================
template <bool LAYER1>
__global__ void __launch_bounds__(256) gather_kernel(
        const float* __restrict__ in, const unsigned* __restrict__ pairs,
        const int* __restrict__ gbase, const int* __restrict__ outdeg,
        const float* __restrict__ b1, float* __restrict__ outbuf,
        float* __restrict__ inv_in) {
    __shared__ int sorted[CAP];        // 16 KB: src ids grouped by local dst
    __shared__ int cnt[NPB];
    __shared__ int start[NPB + 1];
    __shared__ int cur[NPB];
    __shared__ float b1s[N_UNITS];
    int tid = threadIdx.x;
    int b = blockIdx.x;
    int ebeg = gbase[b];
    int ecnt = min(gbase[b + 1] - ebeg, CAP);
    if (tid < NPB) cnt[tid] = 0;
    if (LAYER1 && tid < N_UNITS) b1s[tid] = b1[tid];
    __syncthreads();

    unsigned stash[16];
    #pragma unroll
    for (int r = 0; r < 16; ++r) {
        int idx = tid + 256 * r;
        if (idx < ecnt) {
            unsigned p = pairs[ebeg + idx];
            stash[r] = p;
            atomicAdd(&cnt[p >> 24], 1);
        }
    }
    __syncthreads();

    if (tid < 64) {
        int v = cnt[tid];
        int inc = v;
        #pragma unroll
        for (int off = 1; off < 64; off <<= 1) {
            int u = __shfl_up(inc, off, 64);
            if (tid >= off) inc += u;
        }
        start[tid + 1] = inc;
        cur[tid] = inc - v;
        if (tid == 0) start[0] = 0;
    }
    __syncthreads();

    #pragma unroll
    for (int r = 0; r < 16; ++r) {
        int idx = tid + 256 * r;
        if (idx < ecnt) {
            unsigned p = stash[r];
            int pos = atomicAdd(&cur[p >> 24], 1);
            sorted[pos] = (int)(p & 0xFFFFFF);
        }
    }
    __syncthreads();

    int w = tid >> 6;
    int lane = tid & 63;
    int q = lane & 7;
    int eo = lane >> 3;
    int nd0 = b * NPB;
    #pragma unroll 1
    for (int p = 0; p < 16; ++p) {
        int nd = w * 16 + p;
        int n = nd0 + nd;
        int beg = start[nd];
        int end = start[nd + 1];
        float ax0 = 0.f, ay0 = 0.f, az0 = 0.f, aw0 = 0.f;
        float ax1 = 0.f, ay1 = 0.f, az1 = 0.f, aw1 = 0.f;
        int e = beg + eo;
        for (; e + 8 < end; e += 16) {
            int s0 = sorted[e];
            int s1 = sorted[e + 8];
            float4 v0 = *(const float4*)(in + (size_t)s0 * N_UNITS + q * 4);
            float4 v1 = *(const float4*)(in + (size_t)s1 * N_UNITS + q * 4);
            ax0 += v0.x; ay0 += v0.y; az0 += v0.z; aw0 += v0.w;
            ax1 += v1.x; ay1 += v1.y; az1 += v1.z; aw1 += v1.w;
        }
        if (e < end) {
            float4 v = *(const float4*)(in + (size_t)sorted[e] * N_UNITS + q * 4);
            ax0 += v.x; ay0 += v.y; az0 += v.z; aw0 += v.w;
        }
        e += 8;
        if (e < end) {
            float4 v = *(const float4*)(in + (size_t)sorted[e] * N_UNITS + q * 4);
            ax1 += v.x; ay1 += v.y; az1 += v.z; aw1 += v.w;
        }
        float sx = ax0 + ax1, sy = ay0 + ay1, sz = az0 + az1, sw = aw0 + aw1;
        #pragma unroll
        for (int st = 8; st < 64; st <<= 1) {
            sx += __shfl_xor(sx, st, 64);
            sy += __shfl_xor(sy, st, 64);
            sz += __shfl_xor(sz, st, 64);
            sw += __shfl_xor(sw, st, 64);
        }
        if (eo == 0 && n < N_NODES) {
            if (LAYER1) {
                float ii = rsqrtf(fmaxf((float)(end - beg), 1.0f));
                float io = rsqrtf(fmaxf((float)outdeg[n], 1.0f));
                float4 r;
                r.x = fmaxf(fmaf(sx, ii, b1s[q * 4 + 0]), 0.0f) * io;
                r.y = fmaxf(fmaf(sy, ii, b1s[q * 4 + 1]), 0.0f) * io;
                r.z = fmaxf(fmaf(sz, ii, b1s[q * 4 + 2]), 0.0f) * io;
                r.w = fmaxf(fmaf(sw, ii, b1s[q * 4 + 3]), 0.0f) * io;
                *(float4*)(outbuf + (size_t)n * N_UNITS + q * 4) = r;
                if (q == 0) inv_in[n] = ii;
            } else {
                *(float4*)(outbuf + (size_t)n * N_UNITS + q * 4) =
                    make_float4(sx, sy, sz, sw);
            }
        }
    }
}

// ================= K7: v = (agg2 @ W2)*inv_in + b2 ; out = log_softmax(v) =================
__global__ void __launch_bounds__(256) finalize_kernel(
        const float* __restrict__ agg2, const float* __restrict__ inv_in,
        const float* __restrict__ W2, const float* __restrict__ b2,
        float* __restrict__ out, int N) {
    __shared__ float W2s[N_UNITS * OUT_FEATS];
    __shared__ float b2s[OUT_FEATS];
    for (int i = threadIdx.x; i < N_UNITS * OUT_FEATS; i += 256) W2s[i] = W2[i];
    if (threadIdx.x < OUT_FEATS) b2s[threadIdx.x] = b2[threadIdx.x];
    __syncthreads();
    int n = blockIdx.x * 256 + threadIdx.x;
    if (n >= N) return;
    float a[N_UNITS];
    const float4* ar = (const float4*)(agg2 + (size_t)n * N_UNITS);
    #pragma unroll
    for (int qq = 0; qq < N_UNITS / 4; ++qq) {
        float4 v = ar[qq];
        a[qq * 4 + 0] = v.x; a[qq * 4 + 1] = v.y; a[qq * 4 + 2] = v.z; a[qq * 4 + 3] = v.w;
    }
    float ii = inv_in[n];
    float s[OUT_FEATS];
    #pragma unroll
    for (int o = 0; o < OUT_FEATS; ++o) s[o] = 0.0f;
    #pragma unroll
    for (int k = 0; k < N_UNITS; ++k) {
        float ak = a[k];
        #pragma unroll
        for (int o = 0; o < OUT_FEATS; ++o) s[o] = fmaf(ak, W2s[k * OUT_FEATS + o], s[o]);
    }
    float mx = -INFINITY;
    #pragma unroll
    for (int o = 0; o < OUT_FEATS; ++o) {
        s[o] = fmaf(s[o], ii, b2s[o]);
        mx = fmaxf(mx, s[o]);
    }
    float sum = 0.0f;
    #pragma unroll
    for (int o = 0; o < OUT_FEATS; ++o) sum += __expf(s[o] - mx);
    float lse = mx + __logf(sum);
    #pragma unroll
    for (int o = 0; o < OUT_FEATS; ++o) s[o] -= lse;
    float4* orow4 = (float4*)(out + (size_t)n * OUT_FEATS);
    #pragma unroll
    for (int qq = 0; qq < OUT_FEATS / 4; ++qq)
        orow4[qq] = make_float4(s[qq * 4], s[qq * 4 + 1], s[qq * 4 + 2], s[qq * 4 + 3]);
}

extern "C" void kernel_launch(void* const* d_in, const int* in_sizes, int n_in,
                              void* d_out, int out_size, void* d_ws, size_t ws_size,
                              hipStream_t stream) {
    const float* x   = (const float*)d_in[0];
    const float* W1  = (const float*)d_in[1];
    const float* b1  = (const float*)d_in[2];
    const float* W2  = (const float*)d_in[3];
    const float* b2  = (const float*)d_in[4];
    const int*   src = (const int*)d_in[5];
    const int*   dst = (const int*)d_in[6];
    float* out = (float*)d_out;

    // -------- workspace layout --------
    // outdeg (int[N]) replaces inv_out at base+0 (zeroed with bucket_count in
    // one 408192-byte memset). partials is gone entirely. pairsA has its own
    // slot (live concurrently with h); h aliases agg2 (h dead after gather1).
    char* base = (char*)d_ws;
    int*      outdeg       = (int*)(base);                  // [N]      400000 B
    int*      bucket_count = (int*)(base + 400000L);        // [NB]     (slot to 408192)
    int*      gbaseA       = (int*)(base + 406400L);        // [NC+1]
    int*      gcursorA     = (int*)(base + 406912L);        // [NC]
    int*      gbase        = (int*)(base + 408192L);        // [NB+1]   8192 B slot
    int*      gcursor      = (int*)(base + 416384L);        // [NB]     8192 B slot
    float*    inv_in       = (float*)(base + 424576L);      // [N]      400000 B
    unsigned* pairs        = (unsigned*)(base + 824576L);   // [E]      12.8 MB
    unsigned* pairsA       = (unsigned*)(base + 13624576L); // [E]      12.8 MB (own slot)
    float*    rprime       = (float*)(base + 26424576L);    // [N*32]
    float*    h            = (float*)(base + 39224576L);    // [N*32] — aliases agg2
    float*    agg2         = (float*)(base + 39224576L);    // [N*32]

    // zero outdeg + bucket_count/gbaseA/gcursorA slots in one shot
    hipMemsetAsync(base, 0, 408192L, stream);

    edgecount_kernel<<<EC_NBLK, 256, 0, stream>>>(src, dst, outdeg, bucket_count);
    scan_kernel<<<1, 1024, 0, stream>>>(bucket_count, gbase, gcursor, gbaseA, gcursorA);

    binAgemm_kernel<<<GHALF + NBLK, 512, 0, stream>>>(
        src, dst, gcursorA, pairsA, x, W1, outdeg, h);
    binBgemm_kernel<<<GHALF + NBLK, 512, 0, stream>>>(
        pairsA, gbaseA, gcursor, pairs, x, W1, outdeg, h);

    gather_kernel<true><<<NB, 256, 0, stream>>>(h, pairs, gbase, outdeg, b1, rprime, inv_in);
    gather_kernel<false><<<NB, 256, 0, stream>>>(rprime, pairs, gbase, outdeg, b1, agg2, inv_in);

    finalize_kernel<<<(N_NODES + 255) / 256, 256, 0, stream>>>(agg2, inv_in, W2, b2, out, N_NODES);
}

// Round 10
// 361.795 us; speedup vs baseline: 1.2966x; 1.2966x over previous
//
#include <hip/hip_runtime.h>
#include <hip/hip_bf16.h>
#include <math.h>

#define N_NODES 100000
#define N_EDGES 3200000
#define IN_FEATS 256
#define N_UNITS 32
#define OUT_FEATS 40

#define NPB 64                       // nodes per fine bucket
#define BSHIFT 6                     // dst >> 6 = fine bucket
#define NB 1563                      // ceil(100000/64) fine buckets
#define CAP 4096                     // max edges per fine bucket (avg 2048)

#define NC 49                        // coarse buckets (2048 nodes each)
#define CSHIFT 11                    // dst >> 11 = coarse bucket
#define CHUNK 8192                   // edges per bin block
#define NBLK ((N_EDGES + CHUNK - 1) / CHUNK)   // 391
#define WIN 128                      // fine-bucket window in pass B

// gemm split: half the nodes ride with binA, half with binB
#define GHALF 391                    // gemm blocks per half (391*128 = 50048 nodes)
#define NSPLIT (GHALF * 128)         // 50048

// outdeg hist riders: 4 slices x 96 stripes, 32KB byte-counter LDS each.
// They ride in binAgemm (independent of binA/gemm); the SWAR reduce rides
// in binBgemm (kernel boundary = partials complete), producing inv_out
// before gather1. gemm writes UNNORMALIZED h; gather1 applies io[src]
// per edge as fmaf (same VALU count as plain add).
#define ODS 32768                    // nodes per slice
#define ODW 8192                     // packed words per slice (32KB)
#define OD_NSL 4
#define OD_STR 96
#define HIST_RIDERS (OD_NSL * OD_STR)          // 384
#define RED_RIDERS ((N_NODES / 4 + 511) / 512) // 49

// ================= K0: per-fine-bucket edge counts (LDS-aggregated) =================
__global__ void __launch_bounds__(256) count_kernel(const int* __restrict__ dst,
                                                    int* __restrict__ bucket_count) {
    __shared__ int lh[NB];
    for (int i = threadIdx.x; i < NB; i += 256) lh[i] = 0;
    __syncthreads();
    const int4* d4 = (const int4*)dst;
    const int total4 = N_EDGES / 4;
    for (int i = blockIdx.x * 256 + threadIdx.x; i < total4; i += gridDim.x * 256) {
        int4 v = d4[i];
        atomicAdd(&lh[v.x >> BSHIFT], 1);
        atomicAdd(&lh[v.y >> BSHIFT], 1);
        atomicAdd(&lh[v.z >> BSHIFT], 1);
        atomicAdd(&lh[v.w >> BSHIFT], 1);
    }
    __syncthreads();
    for (int i = threadIdx.x; i < NB; i += 256)
        if (lh[i]) atomicAdd(&bucket_count[i], lh[i]);
}

// ================= K1: exclusive scan of fine counts; derive coarse bases =================
__global__ void __launch_bounds__(1024) scan_kernel(const int* __restrict__ bucket_count,
                                                    int* __restrict__ gbase,
                                                    int* __restrict__ gcursor,
                                                    int* __restrict__ gbaseA,
                                                    int* __restrict__ gcursorA) {
    __shared__ int ps[1024];
    int t = threadIdx.x;
    int i0 = 2 * t, i1 = 2 * t + 1;
    int a = (i0 < NB) ? bucket_count[i0] : 0;
    int b = (i1 < NB) ? bucket_count[i1] : 0;
    ps[t] = a + b;
    __syncthreads();
    for (int off = 1; off < 1024; off <<= 1) {
        int v = (t >= off) ? ps[t - off] : 0;
        __syncthreads();
        ps[t] += v;
        __syncthreads();
    }
    int excl = ps[t] - (a + b);
    if (i0 < NB) { gbase[i0] = excl; gcursor[i0] = excl; }
    if (i1 <= NB) { gbase[i1] = excl + a; if (i1 < NB) gcursor[i1] = excl + a; }
    __syncthreads();
    if (t < NC) { int v = gbase[t * 32]; gbaseA[t] = v; gcursorA[t] = v; }
    if (t == NC) gbaseA[NC] = N_EDGES;
}

// ---- shared gemm body (writes UNNORMALIZED h) ----
__device__ __forceinline__ void gemm_body(char* smem, int tid, int gblk,
                                          const float* __restrict__ x,
                                          const float* __restrict__ W1,
                                          float* __restrict__ h, int nbase) {
    float* Ws = (float*)smem;               // 32 KB
    for (int idx = tid; idx < IN_FEATS * N_UNITS / 4; idx += 512)
        ((float4*)Ws)[idx] = ((const float4*)W1)[idx];
    __syncthreads();
    unsigned n = (unsigned)(nbase + gblk * 128) + (tid >> 2);
    if (n >= (unsigned)N_NODES) return;
    unsigned j0 = (tid & 3) * 8;
    float acc[8] = {0, 0, 0, 0, 0, 0, 0, 0};
    const float4* xr = (const float4*)(x + (size_t)n * IN_FEATS);
    #pragma unroll 4
    for (int k4 = 0; k4 < IN_FEATS / 4; ++k4) {
        float4 xv = xr[k4];
        const float* wk = Ws + (k4 * 4) * N_UNITS + j0;
        #pragma unroll
        for (int jj = 0; jj < 8; ++jj) acc[jj] = fmaf(xv.x, wk[jj], acc[jj]);
        #pragma unroll
        for (int jj = 0; jj < 8; ++jj) acc[jj] = fmaf(xv.y, wk[N_UNITS + jj], acc[jj]);
        #pragma unroll
        for (int jj = 0; jj < 8; ++jj) acc[jj] = fmaf(xv.z, wk[2 * N_UNITS + jj], acc[jj]);
        #pragma unroll
        for (int jj = 0; jj < 8; ++jj) acc[jj] = fmaf(xv.w, wk[3 * N_UNITS + jj], acc[jj]);
    }
    float* hr = h + (size_t)n * N_UNITS + j0;
    #pragma unroll
    for (int jj = 0; jj < 8; ++jj) hr[jj] = acc[jj];
}

// ================= K2: gemm(lo) + coarse binning (binA) + outdeg hist riders =================
__global__ void __launch_bounds__(512) binAgemm_kernel(const int* __restrict__ src,
                                                       const int* __restrict__ dst,
                                                       int* __restrict__ gcursorA,
                                                       unsigned* __restrict__ pairsA,
                                                       const float* __restrict__ x,
                                                       const float* __restrict__ W1,
                                                       float* __restrict__ h,
                                                       unsigned* __restrict__ partials) {
    __shared__ __align__(16) char smem[CHUNK * 4 + 4 * NC * 4];   // 32 KB + 784 B
    int tid = threadIdx.x;
    if (blockIdx.x < GHALF) {
        gemm_body(smem, tid, blockIdx.x, x, W1, h, 0);
        return;
    }
    if (blockIdx.x >= GHALF + NBLK) {
        // ---- hist rider: 32KB byte-counter slice of outdeg ----
        unsigned* lh = (unsigned*)smem;                  // 8192 words
        int r = blockIdx.x - (GHALF + NBLK);             // 0..383
        int slice = r / OD_STR;
        int stripe = r % OD_STR;
        for (int i = tid; i < ODW; i += 512) lh[i] = 0;
        __syncthreads();
        int lo = slice * ODS;
        const int4* s4 = (const int4*)src;
        const int total4 = N_EDGES / 4;
        for (int i = stripe * 512 + tid; i < total4; i += OD_STR * 512) {
            int4 v = s4[i];
            unsigned a = (unsigned)(v.x - lo); if (a < ODS) atomicAdd(&lh[a >> 2], 1u << ((a & 3) * 8));
            unsigned b = (unsigned)(v.y - lo); if (b < ODS) atomicAdd(&lh[b >> 2], 1u << ((b & 3) * 8));
            unsigned c = (unsigned)(v.z - lo); if (c < ODS) atomicAdd(&lh[c >> 2], 1u << ((c & 3) * 8));
            unsigned d = (unsigned)(v.w - lo); if (d < ODS) atomicAdd(&lh[d >> 2], 1u << ((d & 3) * 8));
        }
        __syncthreads();
        int4* dstp = (int4*)(partials + (size_t)r * ODW);
        const int4* lh4 = (const int4*)lh;
        for (int i = tid; i < ODW / 4; i += 512) dstp[i] = lh4[i];
        return;
    }
    // ---- binA: coarse binning (49 bins), LDS sort + coalesced write ----
    unsigned* sortedA = (unsigned*)smem;
    int* hist   = (int*)(smem + CHUNK * 4);
    int* lstart = hist + NC;
    int* cur    = lstart + NC;
    int* gres   = cur + NC;
    int e0 = (blockIdx.x - GHALF) * CHUNK;
    int cnt = min(CHUNK, N_EDGES - e0);
    unsigned es[16], ed[16];
    #pragma unroll
    for (int r = 0; r < 16; ++r) {
        int idx = tid + 512 * r;
        if (idx < cnt) { es[r] = src[e0 + idx]; ed[r] = dst[e0 + idx]; }
    }
    if (tid < NC) hist[tid] = 0;
    __syncthreads();
    #pragma unroll
    for (int r = 0; r < 16; ++r) {
        int idx = tid + 512 * r;
        if (idx < cnt) atomicAdd(&hist[ed[r] >> CSHIFT], 1);
    }
    __syncthreads();
    if (tid < 64) {
        int v = (tid < NC) ? hist[tid] : 0;
        int inc = v;
        #pragma unroll
        for (int off = 1; off < 64; off <<= 1) {
            int u = __shfl_up(inc, off, 64);
            if ((tid & 63) >= off) inc += u;
        }
        if (tid < NC) {
            int ls = inc - v;
            lstart[tid] = ls;
            cur[tid] = ls;
            gres[tid] = atomicAdd(&gcursorA[tid], v) - ls;   // dest = gres[c] + i
        }
    }
    __syncthreads();
    #pragma unroll
    for (int r = 0; r < 16; ++r) {
        int idx = tid + 512 * r;
        if (idx < cnt) {
            int c = ed[r] >> CSHIFT;
            int pos = atomicAdd(&cur[c], 1);
            sortedA[pos] = es[r] | ((ed[r] & ((1u << CSHIFT) - 1)) << 17);
        }
    }
    __syncthreads();
    for (int i = tid; i < cnt; i += 512) {
        int lo = 0, hi = NC - 1;            // largest c with lstart[c] <= i
        while (lo < hi) { int mid = (lo + hi + 1) >> 1; if (lstart[mid] <= i) lo = mid; else hi = mid - 1; }
        pairsA[gres[lo] + i] = sortedA[i];
    }
}

// ================= K3: gemm(hi) + fine binning (binB) + SWAR-reduce riders =================
__global__ void __launch_bounds__(512) binBgemm_kernel(const unsigned* __restrict__ pairsA,
                                                       const int* __restrict__ gbaseA,
                                                       int* __restrict__ gcursor,
                                                       unsigned* __restrict__ pairs,
                                                       const float* __restrict__ x,
                                                       const float* __restrict__ W1,
                                                       float* __restrict__ h,
                                                       const unsigned* __restrict__ partials,
                                                       float* __restrict__ inv_out) {
    __shared__ __align__(16) char smem[CHUNK * 4 + 4 * WIN * 4 + (NC + 2) * 4];  // ~35 KB
    int tid = threadIdx.x;
    if (blockIdx.x < GHALF) {
        gemm_body(smem, tid, blockIdx.x, x, W1, h, NSPLIT);
        return;
    }
    if (blockIdx.x >= GHALF + NBLK) {
        // ---- reduce rider: sum 96 stripes of packed bytes -> inv_out floats ----
        int w = (blockIdx.x - (GHALF + NBLK)) * 512 + tid;   // word = node/4
        if (w >= N_NODES / 4) return;
        int slice = w >> 13;                                  // w / ODW
        int wloc = w & (ODW - 1);
        const unsigned* p = partials + ((size_t)slice * OD_STR) * ODW + wloc;
        unsigned s = 0;
        #pragma unroll 8
        for (int j = 0; j < OD_STR; ++j) s += p[(size_t)j * ODW];
        float4 r;
        r.x = rsqrtf(fmaxf((float)(s & 0xFF), 1.0f));
        r.y = rsqrtf(fmaxf((float)((s >> 8) & 0xFF), 1.0f));
        r.z = rsqrtf(fmaxf((float)((s >> 16) & 0xFF), 1.0f));
        r.w = rsqrtf(fmaxf((float)(s >> 24), 1.0f));
        *(float4*)(inv_out + 4 * w) = r;
        return;
    }
    unsigned* sortedB = (unsigned*)smem;
    int* hist   = (int*)(smem + CHUNK * 4);
    int* lstart = hist + WIN;
    int* cur    = lstart + WIN;
    int* gres   = cur + WIN;
    int* gA     = gres + WIN;                // NC+1 ints
    if (tid <= NC) gA[tid] = gbaseA[tid];
    if (tid < WIN) hist[tid] = 0;
    int e0 = (blockIdx.x - GHALF) * CHUNK;
    int cnt = min(CHUNK, N_EDGES - e0);
    __syncthreads();
    int c0 = 0;
    { int lo = 0, hi = NC - 1;
      while (lo < hi) { int mid = (lo + hi + 1) >> 1; if (gA[mid] <= e0) lo = mid; else hi = mid - 1; }
      c0 = lo; }
    int w0 = c0 * 32;
    unsigned pv[16]; short fw[16];
    int c = c0;
    #pragma unroll
    for (int r = 0; r < 16; ++r) {
        int idx = tid + 512 * r;
        if (idx < cnt) {
            int pos = e0 + idx;
            while (pos >= gA[c + 1]) ++c;
            unsigned p = pairsA[pos];
            unsigned srcid = p & 0x1FFFF;
            unsigned dl11 = (p >> 17) & 0x7FF;
            int wi = (c - c0) * 32 + (int)(dl11 >> 6);
            atomicAdd(&hist[wi], 1);
            pv[r] = srcid | ((dl11 & 63u) << 24);
            fw[r] = (short)wi;
        }
    }
    __syncthreads();
    if (tid < 64) {
        int v0 = hist[2 * tid], v1 = hist[2 * tid + 1];
        int s = v0 + v1;
        int inc = s;
        #pragma unroll
        for (int off = 1; off < 64; off <<= 1) {
            int u = __shfl_up(inc, off, 64);
            if ((tid & 63) >= off) inc += u;
        }
        int excl = inc - s;
        lstart[2 * tid] = excl;      cur[2 * tid] = excl;
        lstart[2 * tid + 1] = excl + v0; cur[2 * tid + 1] = excl + v0;
        int f0 = w0 + 2 * tid, f1 = f0 + 1;
        gres[2 * tid]     = (f0 < NB) ? (atomicAdd(&gcursor[f0], v0) - excl) : 0;
        gres[2 * tid + 1] = (f1 < NB) ? (atomicAdd(&gcursor[f1], v1) - (excl + v0)) : 0;
    }
    __syncthreads();
    #pragma unroll
    for (int r = 0; r < 16; ++r) {
        int idx = tid + 512 * r;
        if (idx < cnt) {
            int pos = atomicAdd(&cur[fw[r]], 1);
            sortedB[pos] = pv[r];
        }
    }
    __syncthreads();
    for (int i = tid; i < cnt; i += 512) {
        int lo = 0, hi = WIN - 1;
        while (lo < hi) { int mid = (lo + hi + 1) >> 1; if (lstart[mid] <= i) lo = mid; else hi = mid - 1; }
        pairs[gres[lo] + i] = sortedB[i];
    }
}

// ================= K5/K6: bucketed gather =================
// LAYER1: h is UNNORMALIZED -> scale each edge contribution by io[src] via fmaf
// (same VALU count as the old plain add; inv_out is 400KB, L2-resident).
template <bool LAYER1>
__global__ void __launch_bounds__(256) gather_kernel(
        const float* __restrict__ in, const unsigned* __restrict__ pairs,
        const int* __restrict__ gbase, const float* __restrict__ inv_out,
        const float* __restrict__ b1, float* __restrict__ outbuf,
        float* __restrict__ inv_in) {
    __shared__ int sorted[CAP];        // 16 KB: src ids grouped by local dst
    __shared__ int cnt[NPB];
    __shared__ int start[NPB + 1];
    __shared__ int cur[NPB];
    __shared__ float b1s[N_UNITS];
    int tid = threadIdx.x;
    int b = blockIdx.x;
    int ebeg = gbase[b];
    int ecnt = min(gbase[b + 1] - ebeg, CAP);
    if (tid < NPB) cnt[tid] = 0;
    if (LAYER1 && tid < N_UNITS) b1s[tid] = b1[tid];
    __syncthreads();

    unsigned stash[16];
    #pragma unroll
    for (int r = 0; r < 16; ++r) {
        int idx = tid + 256 * r;
        if (idx < ecnt) {
            unsigned p = pairs[ebeg + idx];
            stash[r] = p;
            atomicAdd(&cnt[p >> 24], 1);
        }
    }
    __syncthreads();

    if (tid < 64) {
        int v = cnt[tid];
        int inc = v;
        #pragma unroll
        for (int off = 1; off < 64; off <<= 1) {
            int u = __shfl_up(inc, off, 64);
            if (tid >= off) inc += u;
        }
        start[tid + 1] = inc;
        cur[tid] = inc - v;
        if (tid == 0) start[0] = 0;
    }
    __syncthreads();

    #pragma unroll
    for (int r = 0; r < 16; ++r) {
        int idx = tid + 256 * r;
        if (idx < ecnt) {
            unsigned p = stash[r];
            int pos = atomicAdd(&cur[p >> 24], 1);
            sorted[pos] = (int)(p & 0xFFFFFF);
        }
    }
    __syncthreads();

    int w = tid >> 6;
    int lane = tid & 63;
    int q = lane & 7;
    int eo = lane >> 3;
    int nd0 = b * NPB;
    #pragma unroll 1
    for (int p = 0; p < 16; ++p) {
        int nd = w * 16 + p;
        int n = nd0 + nd;
        int beg = start[nd];
        int end = start[nd + 1];
        float ax0 = 0.f, ay0 = 0.f, az0 = 0.f, aw0 = 0.f;
        float ax1 = 0.f, ay1 = 0.f, az1 = 0.f, aw1 = 0.f;
        int e = beg + eo;
        for (; e + 8 < end; e += 16) {
            int s0 = sorted[e];
            int s1 = sorted[e + 8];
            float4 v0 = *(const float4*)(in + (size_t)s0 * N_UNITS + q * 4);
            float4 v1 = *(const float4*)(in + (size_t)s1 * N_UNITS + q * 4);
            if (LAYER1) {
                float io0 = inv_out[s0];
                float io1 = inv_out[s1];
                ax0 = fmaf(v0.x, io0, ax0); ay0 = fmaf(v0.y, io0, ay0);
                az0 = fmaf(v0.z, io0, az0); aw0 = fmaf(v0.w, io0, aw0);
                ax1 = fmaf(v1.x, io1, ax1); ay1 = fmaf(v1.y, io1, ay1);
                az1 = fmaf(v1.z, io1, az1); aw1 = fmaf(v1.w, io1, aw1);
            } else {
                ax0 += v0.x; ay0 += v0.y; az0 += v0.z; aw0 += v0.w;
                ax1 += v1.x; ay1 += v1.y; az1 += v1.z; aw1 += v1.w;
            }
        }
        if (e < end) {
            int s0 = sorted[e];
            float4 v = *(const float4*)(in + (size_t)s0 * N_UNITS + q * 4);
            if (LAYER1) {
                float io0 = inv_out[s0];
                ax0 = fmaf(v.x, io0, ax0); ay0 = fmaf(v.y, io0, ay0);
                az0 = fmaf(v.z, io0, az0); aw0 = fmaf(v.w, io0, aw0);
            } else {
                ax0 += v.x; ay0 += v.y; az0 += v.z; aw0 += v.w;
            }
        }
        e += 8;
        if (e < end) {
            int s1 = sorted[e];
            float4 v = *(const float4*)(in + (size_t)s1 * N_UNITS + q * 4);
            if (LAYER1) {
                float io1 = inv_out[s1];
                ax1 = fmaf(v.x, io1, ax1); ay1 = fmaf(v.y, io1, ay1);
                az1 = fmaf(v.z, io1, az1); aw1 = fmaf(v.w, io1, aw1);
            } else {
                ax1 += v.x; ay1 += v.y; az1 += v.z; aw1 += v.w;
            }
        }
        float sx = ax0 + ax1, sy = ay0 + ay1, sz = az0 + az1, sw = aw0 + aw1;
        #pragma unroll
        for (int st = 8; st < 64; st <<= 1) {
            sx += __shfl_xor(sx, st, 64);
            sy += __shfl_xor(sy, st, 64);
            sz += __shfl_xor(sz, st, 64);
            sw += __shfl_xor(sw, st, 64);
        }
        if (eo == 0 && n < N_NODES) {
            if (LAYER1) {
                float ii = rsqrtf(fmaxf((float)(end - beg), 1.0f));
                float io = inv_out[n];
                float4 r;
                r.x = fmaxf(fmaf(sx, ii, b1s[q * 4 + 0]), 0.0f) * io;
                r.y = fmaxf(fmaf(sy, ii, b1s[q * 4 + 1]), 0.0f) * io;
                r.z = fmaxf(fmaf(sz, ii, b1s[q * 4 + 2]), 0.0f) * io;
                r.w = fmaxf(fmaf(sw, ii, b1s[q * 4 + 3]), 0.0f) * io;
                *(float4*)(outbuf + (size_t)n * N_UNITS + q * 4) = r;
                if (q == 0) inv_in[n] = ii;
            } else {
                *(float4*)(outbuf + (size_t)n * N_UNITS + q * 4) =
                    make_float4(sx, sy, sz, sw);
            }
        }
    }
}

// ================= K7: v = (agg2 @ W2)*inv_in + b2 ; out = log_softmax(v) =================
__global__ void __launch_bounds__(256) finalize_kernel(
        const float* __restrict__ agg2, const float* __restrict__ inv_in,
        const float* __restrict__ W2, const float* __restrict__ b2,
        float* __restrict__ out, int N) {
    __shared__ float W2s[N_UNITS * OUT_FEATS];
    __shared__ float b2s[OUT_FEATS];
    for (int i = threadIdx.x; i < N_UNITS * OUT_FEATS; i += 256) W2s[i] = W2[i];
    if (threadIdx.x < OUT_FEATS) b2s[threadIdx.x] = b2[threadIdx.x];
    __syncthreads();
    int n = blockIdx.x * 256 + threadIdx.x;
    if (n >= N) return;
    float a[N_UNITS];
    const float4* ar = (const float4*)(agg2 + (size_t)n * N_UNITS);
    #pragma unroll
    for (int qq = 0; qq < N_UNITS / 4; ++qq) {
        float4 v = ar[qq];
        a[qq * 4 + 0] = v.x; a[qq * 4 + 1] = v.y; a[qq * 4 + 2] = v.z; a[qq * 4 + 3] = v.w;
    }
    float ii = inv_in[n];
    float s[OUT_FEATS];
    #pragma unroll
    for (int o = 0; o < OUT_FEATS; ++o) s[o] = 0.0f;
    #pragma unroll
    for (int k = 0; k < N_UNITS; ++k) {
        float ak = a[k];
        #pragma unroll
        for (int o = 0; o < OUT_FEATS; ++o) s[o] = fmaf(ak, W2s[k * OUT_FEATS + o], s[o]);
    }
    float mx = -INFINITY;
    #pragma unroll
    for (int o = 0; o < OUT_FEATS; ++o) {
        s[o] = fmaf(s[o], ii, b2s[o]);
        mx = fmaxf(mx, s[o]);
    }
    float sum = 0.0f;
    #pragma unroll
    for (int o = 0; o < OUT_FEATS; ++o) sum += __expf(s[o] - mx);
    float lse = mx + __logf(sum);
    #pragma unroll
    for (int o = 0; o < OUT_FEATS; ++o) s[o] -= lse;
    float4* orow4 = (float4*)(out + (size_t)n * OUT_FEATS);
    #pragma unroll
    for (int qq = 0; qq < OUT_FEATS / 4; ++qq)
        orow4[qq] = make_float4(s[qq * 4], s[qq * 4 + 1], s[qq * 4 + 2], s[qq * 4 + 3]);
}

extern "C" void kernel_launch(void* const* d_in, const int* in_sizes, int n_in,
                              void* d_out, int out_size, void* d_ws, size_t ws_size,
                              hipStream_t stream) {
    const float* x   = (const float*)d_in[0];
    const float* W1  = (const float*)d_in[1];
    const float* b1  = (const float*)d_in[2];
    const float* W2  = (const float*)d_in[3];
    const float* b2  = (const float*)d_in[4];
    const int*   src = (const int*)d_in[5];
    const int*   dst = (const int*)d_in[6];
    float* out = (float*)d_out;

    // -------- workspace layout --------
    // inv_out float[N] at base. partials (384*32KB = 12.3MB) lives in the
    // rprime slot: written by hist riders (K2), read by reduce riders (K3),
    // dead before gather1 writes rprime. pairsA own slot; h aliases agg2.
    char* base = (char*)d_ws;
    float*    inv_out      = (float*)(base);                // [N]      400000 B
    int*      bucket_count = (int*)(base + 400000L);        // [NB]     (slot to 408192)
    int*      gbaseA       = (int*)(base + 406400L);        // [NC+1]
    int*      gcursorA     = (int*)(base + 406912L);        // [NC]
    int*      gbase        = (int*)(base + 408192L);        // [NB+1]   8192 B slot
    int*      gcursor      = (int*)(base + 416384L);        // [NB]     8192 B slot
    float*    inv_in       = (float*)(base + 424576L);      // [N]      400000 B
    unsigned* pairs        = (unsigned*)(base + 824576L);   // [E]      12.8 MB
    unsigned* pairsA       = (unsigned*)(base + 13624576L); // [E]      12.8 MB (own slot)
    float*    rprime       = (float*)(base + 26424576L);    // [N*32]
    float*    h            = (float*)(base + 39224576L);    // [N*32] — aliases agg2
    float*    agg2         = (float*)(base + 39224576L);    // [N*32]
    unsigned* partials     = (unsigned*)rprime;             // 12.3 MB over rprime

    // zero bucket_count slot only
    hipMemsetAsync(bucket_count, 0, 8192L, stream);

    count_kernel<<<128, 256, 0, stream>>>(dst, bucket_count);
    scan_kernel<<<1, 1024, 0, stream>>>(bucket_count, gbase, gcursor, gbaseA, gcursorA);

    binAgemm_kernel<<<GHALF + NBLK + HIST_RIDERS, 512, 0, stream>>>(
        src, dst, gcursorA, pairsA, x, W1, h, partials);
    binBgemm_kernel<<<GHALF + NBLK + RED_RIDERS, 512, 0, stream>>>(
        pairsA, gbaseA, gcursor, pairs, x, W1, h, partials, inv_out);

    gather_kernel<true><<<NB, 256, 0, stream>>>(h, pairs, gbase, inv_out, b1, rprime, inv_in);
    gather_kernel<false><<<NB, 256, 0, stream>>>(rprime, pairs, gbase, inv_out, b1, agg2, inv_in);

    finalize_kernel<<<(N_NODES + 255) / 256, 256, 0, stream>>>(agg2, inv_in, W2, b2, out, N_NODES);
}